// Round 1
// baseline (3078.722 us; speedup 1.0000x reference)
//
#include <hip/hip_runtime.h>
#include <math.h>

#define NTOK 8192   // B*S = 4*2048
#define DDIM 1024
#define NEXP 8
#define FDIM 4096

typedef short bf16x8 __attribute__((ext_vector_type(8)));
typedef float f32x4 __attribute__((ext_vector_type(4)));

static __device__ __forceinline__ unsigned short f2bf(float f) {
  unsigned int u = __float_as_uint(f);
  u += 0x7fffu + ((u >> 16) & 1u);
  return (unsigned short)(u >> 16);
}

// ---------------- router: logits, softmax, gate, normalized gate ----------------
__global__ __launch_bounds__(256) void router_kernel(
    const float* __restrict__ x, const float* __restrict__ prev,
    const float* __restrict__ Wt, const float* __restrict__ Wgt,
    const float* __restrict__ Wel,
    float* __restrict__ gn, float* __restrict__ logits_out)
{
  __shared__ float wt_s[NEXP * DDIM];   // 32 KB
  const int tid = threadIdx.x;
  for (int i = tid; i < NEXP * DDIM; i += 256) wt_s[i] = Wt[i];
  __syncthreads();
  const int lane = tid & 63;
  const int t = blockIdx.x * 4 + (tid >> 6);   // one wave per token

  const float* xr = x + (size_t)t * DDIM;
  float acc[NEXP];
#pragma unroll
  for (int e = 0; e < NEXP; ++e) acc[e] = 0.f;
  for (int k = lane; k < DDIM; k += 64) {
    float xv = xr[k];
#pragma unroll
    for (int e = 0; e < NEXP; ++e) acc[e] += xv * wt_s[e * DDIM + k];
  }
#pragma unroll
  for (int e = 0; e < NEXP; ++e) {
    float v = acc[e];
#pragma unroll
    for (int off = 32; off >= 1; off >>= 1) v += __shfl_xor(v, off);
    acc[e] = v;
  }
  float pl[NEXP];
#pragma unroll
  for (int e = 0; e < NEXP; ++e) pl[e] = prev[(size_t)t * NEXP + e];
#pragma unroll
  for (int e = 0; e < NEXP; ++e) {
    float s = acc[e];
#pragma unroll
    for (int e2 = 0; e2 < NEXP; ++e2) s += pl[e2] * Wgt[e * NEXP + e2];
    acc[e] = s;
  }
  // softmax (fp32, matches ref closely for the data-dependent mask)
  float mx = acc[0];
#pragma unroll
  for (int e = 1; e < NEXP; ++e) mx = fmaxf(mx, acc[e]);
  float st[NEXP]; float se = 0.f;
#pragma unroll
  for (int e = 0; e < NEXP; ++e) { st[e] = expf(acc[e] - mx); se += st[e]; }
  float inv = 1.f / se;
  float g[NEXP]; float gs = 0.f;
#pragma unroll
  for (int e = 0; e < NEXP; ++e) {
    float s = st[e] * inv;
    float we = 1.f / (1.f + expf(-Wel[e]));
    float gg = (s > 0.5f * we) ? s : 0.f;   // LAMBDA_SCALE = 0.5
    g[e] = gg; gs += gg;
  }
  float r = 1.f / (gs + 1e-6f);
  if (lane < NEXP) {
    gn[(size_t)t * NEXP + lane] = g[lane] * r;           // normalized gate
    logits_out[(size_t)t * NEXP + lane] = acc[lane];     // output 1
  }
}

// ---------------- x f32 -> bf16 ----------------
__global__ __launch_bounds__(256) void cast_kernel(
    const float* __restrict__ in, unsigned short* __restrict__ out)
{
  size_t i = ((size_t)blockIdx.x * 256 + threadIdx.x) * 8;
  float4 a = *(const float4*)(in + i);
  float4 b = *(const float4*)(in + i + 4);
  unsigned short tb[8];
  tb[0]=f2bf(a.x); tb[1]=f2bf(a.y); tb[2]=f2bf(a.z); tb[3]=f2bf(a.w);
  tb[4]=f2bf(b.x); tb[5]=f2bf(b.y); tb[6]=f2bf(b.z); tb[7]=f2bf(b.w);
  *(uint4*)(out + i) = *(const uint4*)tb;
}

// ---------------- y := sum_e gn[t,e] * b2[e,:] ----------------
__global__ __launch_bounds__(256) void y_init_kernel(
    const float* __restrict__ gn, const float* __restrict__ b2,
    float* __restrict__ y)
{
  const int t = blockIdx.y;
  const int d = blockIdx.x * 256 + threadIdx.x;
  float s = 0.f;
#pragma unroll
  for (int e = 0; e < NEXP; ++e) s += gn[(size_t)t * NEXP + e] * b2[(size_t)e * DDIM + d];
  y[(size_t)t * DDIM + d] = s;
}

// ---------------- GEMM1: h' = gn * gelu(xb @ W1e + b1e), bf16 out ----------------
__global__ __launch_bounds__(256) void gemm1_gelu(
    const unsigned short* __restrict__ xb,   // [NTOK][DDIM] bf16
    const float* __restrict__ W1e,           // [DDIM][FDIM] f32
    const float* __restrict__ b1e,           // [FDIM]
    const float* __restrict__ gn,            // [NTOK][NEXP]
    int e,
    unsigned short* __restrict__ hb)         // [NTOK][FDIM] bf16
{
  __shared__ unsigned short As[128 * 40];    // A tile [m][k], stride 40 pads banks
  __shared__ unsigned short Bs[128 * 40];    // B^T tile [n][k]
  __shared__ float gns[128];
  __shared__ float b1s[128];
  const int tid = threadIdx.x;
  const int m0 = blockIdx.y * 128, n0 = blockIdx.x * 128;
  if (tid < 128) {
    gns[tid] = gn[(size_t)(m0 + tid) * NEXP + e];
    b1s[tid] = b1e[n0 + tid];
  }
  f32x4 acc[4][4];
#pragma unroll
  for (int i = 0; i < 4; ++i)
#pragma unroll
    for (int j = 0; j < 4; ++j) acc[i][j] = (f32x4){0.f, 0.f, 0.f, 0.f};

  const int arow = tid >> 1, ahalf = tid & 1;
  const int bk = tid & 31, bn = (tid >> 5) * 16;
  const int lane = tid & 63;
  const int wm = ((tid >> 6) >> 1) * 64, wn = ((tid >> 6) & 1) * 64;
  const int fr = lane & 15, fk = (lane >> 4) * 8;

  const unsigned short* ag = xb + (size_t)(m0 + arow) * DDIM + ahalf * 16;
  const float* bg = W1e + (size_t)bk * FDIM + n0 + bn;

  for (int k0 = 0; k0 < DDIM; k0 += 32) {
    uint4 a0 = *(const uint4*)(ag + k0);
    uint4 a1 = *(const uint4*)(ag + k0 + 8);
    const float* bp = bg + (size_t)k0 * FDIM;
    float4 f0 = *(const float4*)(bp);
    float4 f1 = *(const float4*)(bp + 4);
    float4 f2 = *(const float4*)(bp + 8);
    float4 f3 = *(const float4*)(bp + 12);
    __syncthreads();
    *(uint4*)&As[arow * 40 + ahalf * 16] = a0;
    *(uint4*)&As[arow * 40 + ahalf * 16 + 8] = a1;
    unsigned short tb[16];
    tb[0]=f2bf(f0.x); tb[1]=f2bf(f0.y); tb[2]=f2bf(f0.z); tb[3]=f2bf(f0.w);
    tb[4]=f2bf(f1.x); tb[5]=f2bf(f1.y); tb[6]=f2bf(f1.z); tb[7]=f2bf(f1.w);
    tb[8]=f2bf(f2.x); tb[9]=f2bf(f2.y); tb[10]=f2bf(f2.z); tb[11]=f2bf(f2.w);
    tb[12]=f2bf(f3.x); tb[13]=f2bf(f3.y); tb[14]=f2bf(f3.z); tb[15]=f2bf(f3.w);
#pragma unroll
    for (int j = 0; j < 16; ++j) Bs[(bn + j) * 40 + bk] = tb[j];
    __syncthreads();
    bf16x8 af[4], bfr[4];
#pragma unroll
    for (int i = 0; i < 4; ++i) af[i] = *(const bf16x8*)&As[(wm + i * 16 + fr) * 40 + fk];
#pragma unroll
    for (int j = 0; j < 4; ++j) bfr[j] = *(const bf16x8*)&Bs[(wn + j * 16 + fr) * 40 + fk];
#pragma unroll
    for (int i = 0; i < 4; ++i)
#pragma unroll
      for (int j = 0; j < 4; ++j)
        acc[i][j] = __builtin_amdgcn_mfma_f32_16x16x32_bf16(af[i], bfr[j], acc[i][j], 0, 0, 0);
  }
#pragma unroll
  for (int i = 0; i < 4; ++i)
#pragma unroll
    for (int j = 0; j < 4; ++j) {
      const int col = wn + j * 16 + fr;
#pragma unroll
      for (int r = 0; r < 4; ++r) {
        const int row = wm + i * 16 + (lane >> 4) * 4 + r;
        float v = acc[i][j][r] + b1s[col];
        v = 0.5f * v * (1.f + erff(v * 0.70710678118654752f));  // exact gelu
        v *= gns[row];
        hb[(size_t)(m0 + row) * FDIM + n0 + col] = f2bf(v);
      }
    }
}

// ---------------- GEMM2: y += hb @ W2e ----------------
__global__ __launch_bounds__(256) void gemm2_acc(
    const unsigned short* __restrict__ hb,   // [NTOK][FDIM] bf16
    const float* __restrict__ W2e,           // [FDIM][DDIM] f32
    float* __restrict__ y)                   // [NTOK][DDIM] f32 accumulate
{
  __shared__ unsigned short As[128 * 40];
  __shared__ unsigned short Bs[128 * 40];
  const int tid = threadIdx.x;
  const int m0 = blockIdx.y * 128, n0 = blockIdx.x * 128;
  f32x4 acc[4][4];
#pragma unroll
  for (int i = 0; i < 4; ++i)
#pragma unroll
    for (int j = 0; j < 4; ++j) acc[i][j] = (f32x4){0.f, 0.f, 0.f, 0.f};

  const int arow = tid >> 1, ahalf = tid & 1;
  const int bk = tid & 31, bn = (tid >> 5) * 16;
  const int lane = tid & 63;
  const int wm = ((tid >> 6) >> 1) * 64, wn = ((tid >> 6) & 1) * 64;
  const int fr = lane & 15, fk = (lane >> 4) * 8;

  const unsigned short* ag = hb + (size_t)(m0 + arow) * FDIM + ahalf * 16;
  const float* bg = W2e + (size_t)bk * DDIM + n0 + bn;

  for (int k0 = 0; k0 < FDIM; k0 += 32) {
    uint4 a0 = *(const uint4*)(ag + k0);
    uint4 a1 = *(const uint4*)(ag + k0 + 8);
    const float* bp = bg + (size_t)k0 * DDIM;
    float4 f0 = *(const float4*)(bp);
    float4 f1 = *(const float4*)(bp + 4);
    float4 f2 = *(const float4*)(bp + 8);
    float4 f3 = *(const float4*)(bp + 12);
    __syncthreads();
    *(uint4*)&As[arow * 40 + ahalf * 16] = a0;
    *(uint4*)&As[arow * 40 + ahalf * 16 + 8] = a1;
    unsigned short tb[16];
    tb[0]=f2bf(f0.x); tb[1]=f2bf(f0.y); tb[2]=f2bf(f0.z); tb[3]=f2bf(f0.w);
    tb[4]=f2bf(f1.x); tb[5]=f2bf(f1.y); tb[6]=f2bf(f1.z); tb[7]=f2bf(f1.w);
    tb[8]=f2bf(f2.x); tb[9]=f2bf(f2.y); tb[10]=f2bf(f2.z); tb[11]=f2bf(f2.w);
    tb[12]=f2bf(f3.x); tb[13]=f2bf(f3.y); tb[14]=f2bf(f3.z); tb[15]=f2bf(f3.w);
#pragma unroll
    for (int j = 0; j < 16; ++j) Bs[(bn + j) * 40 + bk] = tb[j];
    __syncthreads();
    bf16x8 af[4], bfr[4];
#pragma unroll
    for (int i = 0; i < 4; ++i) af[i] = *(const bf16x8*)&As[(wm + i * 16 + fr) * 40 + fk];
#pragma unroll
    for (int j = 0; j < 4; ++j) bfr[j] = *(const bf16x8*)&Bs[(wn + j * 16 + fr) * 40 + fk];
#pragma unroll
    for (int i = 0; i < 4; ++i)
#pragma unroll
      for (int j = 0; j < 4; ++j)
        acc[i][j] = __builtin_amdgcn_mfma_f32_16x16x32_bf16(af[i], bfr[j], acc[i][j], 0, 0, 0);
  }
#pragma unroll
  for (int i = 0; i < 4; ++i)
#pragma unroll
    for (int j = 0; j < 4; ++j) {
      const int col = wn + j * 16 + fr;
#pragma unroll
      for (int r = 0; r < 4; ++r) {
        const int row = wm + i * 16 + (lane >> 4) * 4 + r;
        float* yp = y + (size_t)(m0 + row) * DDIM + n0 + col;
        *yp += acc[i][j][r];
      }
    }
}

extern "C" void kernel_launch(void* const* d_in, const int* in_sizes, int n_in,
                              void* d_out, int out_size, void* d_ws, size_t ws_size,
                              hipStream_t stream) {
  (void)in_sizes; (void)n_in; (void)out_size; (void)ws_size;
  const float* x    = (const float*)d_in[0];
  const float* prev = (const float*)d_in[1];
  const float* Wt   = (const float*)d_in[2];
  const float* Wgt  = (const float*)d_in[3];
  const float* Wel  = (const float*)d_in[4];
  const float* W1   = (const float*)d_in[5];
  const float* b1   = (const float*)d_in[6];
  const float* W2   = (const float*)d_in[7];
  const float* b2   = (const float*)d_in[8];

  float* y      = (float*)d_out;                       // [NTOK][DDIM]
  float* logits = y + (size_t)NTOK * DDIM;             // [NTOK][NEXP]

  char* ws = (char*)d_ws;
  float* gn          = (float*)ws;                                   // 256 KB
  unsigned short* xb = (unsigned short*)(ws + (1 << 18));            // 16 MB
  unsigned short* hb = (unsigned short*)(ws + (1 << 18) + (1 << 24)); // 64 MB

  router_kernel<<<dim3(NTOK / 4), dim3(256), 0, stream>>>(x, prev, Wt, Wgt, Wel, gn, logits);
  cast_kernel<<<dim3((NTOK * DDIM) / (8 * 256)), dim3(256), 0, stream>>>(x, xb);
  y_init_kernel<<<dim3(DDIM / 256, NTOK), dim3(256), 0, stream>>>(gn, b2, y);

  for (int e = 0; e < NEXP; ++e) {
    gemm1_gelu<<<dim3(FDIM / 128, NTOK / 128), dim3(256), 0, stream>>>(
        xb, W1 + (size_t)e * DDIM * FDIM, b1 + (size_t)e * FDIM, gn, e, hb);
    gemm2_acc<<<dim3(DDIM / 128, NTOK / 128), dim3(256), 0, stream>>>(
        hb, W2 + (size_t)e * FDIM * DDIM, y);
  }
}

// Round 2
// 575.155 us; speedup vs baseline: 5.3529x; 5.3529x over previous
//
#include <hip/hip_runtime.h>
#include <math.h>

#define NTOK 8192   // B*S
#define DDIM 1024
#define NEXP 8
#define FDIM 4096
#define MAXROWS 25600   // <=3 active experts/token (softmax sum bound) + per-expert pad

typedef short bf16x8 __attribute__((ext_vector_type(8)));
typedef float f32x4 __attribute__((ext_vector_type(4)));

static __device__ __forceinline__ unsigned short f2bf(float f) {
  unsigned int u = __float_as_uint(f);
  u += 0x7fffu + ((u >> 16) & 1u);
  return (unsigned short)(u >> 16);
}

static __device__ __forceinline__ void gl_lds16(const void* g, void* l) {
  __builtin_amdgcn_global_load_lds(
      (const __attribute__((address_space(1))) unsigned int*)g,
      (__attribute__((address_space(3))) unsigned int*)l, 16, 0, 0);
}

// ---------------- router (fp32, mask-exact) ----------------
__global__ __launch_bounds__(256) void router_kernel(
    const float* __restrict__ x, const float* __restrict__ prev,
    const float* __restrict__ Wt, const float* __restrict__ Wgt,
    const float* __restrict__ Wel,
    float* __restrict__ gn, float* __restrict__ logits_out)
{
  __shared__ float wt_s[NEXP * DDIM];
  const int tid = threadIdx.x;
  for (int i = tid; i < NEXP * DDIM; i += 256) wt_s[i] = Wt[i];
  __syncthreads();
  const int lane = tid & 63;
  const int t = blockIdx.x * 4 + (tid >> 6);

  const float* xr = x + (size_t)t * DDIM;
  float acc[NEXP];
#pragma unroll
  for (int e = 0; e < NEXP; ++e) acc[e] = 0.f;
  for (int k = lane; k < DDIM; k += 64) {
    float xv = xr[k];
#pragma unroll
    for (int e = 0; e < NEXP; ++e) acc[e] += xv * wt_s[e * DDIM + k];
  }
#pragma unroll
  for (int e = 0; e < NEXP; ++e) {
    float v = acc[e];
#pragma unroll
    for (int off = 32; off >= 1; off >>= 1) v += __shfl_xor(v, off);
    acc[e] = v;
  }
  float pl[NEXP];
#pragma unroll
  for (int e = 0; e < NEXP; ++e) pl[e] = prev[(size_t)t * NEXP + e];
#pragma unroll
  for (int e = 0; e < NEXP; ++e) {
    float s = acc[e];
#pragma unroll
    for (int e2 = 0; e2 < NEXP; ++e2) s += pl[e2] * Wgt[e * NEXP + e2];
    acc[e] = s;
  }
  float mx = acc[0];
#pragma unroll
  for (int e = 1; e < NEXP; ++e) mx = fmaxf(mx, acc[e]);
  float st[NEXP]; float se = 0.f;
#pragma unroll
  for (int e = 0; e < NEXP; ++e) { st[e] = expf(acc[e] - mx); se += st[e]; }
  float inv = 1.f / se;
  float g[NEXP]; float gs = 0.f;
#pragma unroll
  for (int e = 0; e < NEXP; ++e) {
    float s = st[e] * inv;
    float we = 1.f / (1.f + expf(-Wel[e]));
    float gg = (s > 0.5f * we) ? s : 0.f;
    g[e] = gg; gs += gg;
  }
  float r = 1.f / (gs + 1e-6f);
  if (lane < NEXP) {
    gn[(size_t)t * NEXP + lane] = g[lane] * r;
    logits_out[(size_t)t * NEXP + lane] = acc[lane];
  }
}

// ---------------- x f32 -> bf16 ----------------
__global__ __launch_bounds__(256) void cast_kernel(
    const float* __restrict__ in, unsigned short* __restrict__ out)
{
  size_t i = ((size_t)blockIdx.x * 256 + threadIdx.x) * 8;
  float4 a = *(const float4*)(in + i);
  float4 b = *(const float4*)(in + i + 4);
  unsigned short tb[8];
  tb[0]=f2bf(a.x); tb[1]=f2bf(a.y); tb[2]=f2bf(a.z); tb[3]=f2bf(a.w);
  tb[4]=f2bf(b.x); tb[5]=f2bf(b.y); tb[6]=f2bf(b.z); tb[7]=f2bf(b.w);
  *(uint4*)(out + i) = *(const uint4*)tb;
}

// ---------------- count active tokens per expert ----------------
__global__ __launch_bounds__(256) void count_kernel(
    const float* __restrict__ gn, int* __restrict__ cnt)
{
  const int e = blockIdx.x, tid = threadIdx.x;
  int c = 0;
  for (int t = tid; t < NTOK; t += 256) c += (gn[(size_t)t * NEXP + e] > 0.f) ? 1 : 0;
#pragma unroll
  for (int o = 32; o >= 1; o >>= 1) c += __shfl_xor(c, o);
  __shared__ int sm[4];
  if ((tid & 63) == 0) sm[tid >> 6] = c;
  __syncthreads();
  if (tid == 0) cnt[e] = sm[0] + sm[1] + sm[2] + sm[3];
}

// ---------------- compact token lists (deterministic, token order) ----------------
__global__ __launch_bounds__(256) void compact_kernel(
    const float* __restrict__ gn, const int* __restrict__ cnt,
    int* __restrict__ offs, int* __restrict__ rowtok, int* __restrict__ rowof)
{
  const int e = blockIdx.x, tid = threadIdx.x;
  int base = 0;
#pragma unroll
  for (int q = 0; q < 8; ++q) if (q < e) base += (cnt[q] + 127) & ~127;
  const int padcnt = (cnt[e] + 127) & ~127;
  if (e == 0 && tid == 0) {
    int a = 0; offs[0] = 0;
#pragma unroll
    for (int q = 0; q < 8; ++q) { a += (cnt[q] + 127) & ~127; offs[q + 1] = a; }
  }
  __shared__ int wsm[4];
  __shared__ int running;
  if (tid == 0) running = 0;
  __syncthreads();
  const int lane = tid & 63, wv = tid >> 6;
  for (int c0 = 0; c0 < NTOK; c0 += 256) {
    const int t = c0 + tid;
    const bool pr = gn[(size_t)t * NEXP + e] > 0.f;
    unsigned long long bal = __ballot(pr);
    int pre = __popcll(bal & ((1ull << lane) - 1ull));
    if (lane == 0) wsm[wv] = __popcll(bal);
    __syncthreads();
    int wbase = 0;
#pragma unroll
    for (int q = 0; q < 4; ++q) if (q < wv) wbase += wsm[q];
    const int tot = wsm[0] + wsm[1] + wsm[2] + wsm[3];
    const int idx = base + running + wbase + pre;
    if (pr) rowtok[idx] = t;
    rowof[(size_t)t * NEXP + e] = pr ? idx : -1;
    __syncthreads();
    if (tid == 0) running += tot;
  }
  __syncthreads();
  for (int i = cnt[e] + tid; i < padcnt; i += 256) rowtok[base + i] = -1;
}

// ---------------- y := sum_e gn*b2 (per-expert path) ----------------
__global__ __launch_bounds__(256) void y_init_kernel(
    const float* __restrict__ gn, const float* __restrict__ b2,
    float* __restrict__ y)
{
  const int t = blockIdx.y;
  const int d = blockIdx.x * 256 + threadIdx.x;
  float s = 0.f;
#pragma unroll
  for (int e = 0; e < NEXP; ++e) s += gn[(size_t)t * NEXP + e] * b2[(size_t)e * DDIM + d];
  y[(size_t)t * DDIM + d] = s;
}

// ---------------- transpose+convert: in f32 [Kin][Nin] -> out bf16 [Nin][Kin] ----------------
__global__ __launch_bounds__(256) void transcvt(
    const float* __restrict__ in, unsigned short* __restrict__ out,
    int Kin, int Nin)
{
  __shared__ float tile[64][65];
  const size_t zo = (size_t)blockIdx.z * Kin * Nin;
  const float* inp = in + zo;
  unsigned short* outp = out + zo;
  const int k0 = blockIdx.y * 64, n0 = blockIdx.x * 64;
  const int tid = threadIdx.x;
  const int r = tid >> 4, c4 = (tid & 15) * 4;
#pragma unroll
  for (int rr = 0; rr < 64; rr += 16) {
    float4 v = *(const float4*)(inp + (size_t)(k0 + r + rr) * Nin + n0 + c4);
    tile[r + rr][c4] = v.x; tile[r + rr][c4 + 1] = v.y;
    tile[r + rr][c4 + 2] = v.z; tile[r + rr][c4 + 3] = v.w;
  }
  __syncthreads();
#pragma unroll
  for (int it = 0; it < 2; ++it) {
    const int o = it * 256 + tid;
    const int n = o >> 3, ks = (o & 7) * 8;
    unsigned short tb[8];
#pragma unroll
    for (int j = 0; j < 8; ++j) tb[j] = f2bf(tile[ks + j][n]);
    *(uint4*)(outp + (size_t)(n0 + n) * Kin + k0 + ks) = *(const uint4*)tb;
  }
}

// ---------------- GEMM1: h' = gn * gelu(gather(xb) @ W1^T) ----------------
__global__ __launch_bounds__(256) void gemm_h(
    const unsigned short* __restrict__ xb,   // [NTOK][DDIM] bf16
    const unsigned short* __restrict__ W,    // [FDIM][DDIM] bf16 (transposed), per-expert stride
    size_t wstride,
    const float* __restrict__ b1,            // [E][FDIM]
    const float* __restrict__ gn,            // [NTOK][E]
    const int* __restrict__ rowtok,
    const int* __restrict__ offs,            // [9], multiples of 128
    int efix,
    unsigned short* __restrict__ hb)         // compact [rows][FDIM] bf16
{
  __shared__ unsigned short As[128 * 32];
  __shared__ unsigned short Bs[128 * 32];
  __shared__ float gns[128];
  __shared__ float b1s[128];
  __shared__ int toks[128];
  const int tid = threadIdx.x;

  int mt, e, hbase;
  if (efix >= 0) {
    e = efix;
    hbase = offs[e];
    mt = (hbase >> 7) + blockIdx.y;
    if (mt * 128 >= offs[e + 1]) return;
  } else {
    mt = blockIdx.y;
    const int r0 = mt * 128;
    if (r0 >= offs[8]) return;
    e = 0;
#pragma unroll
    for (int q = 1; q < 8; ++q) if (r0 >= offs[q]) e = q;
    hbase = 0;
  }
  const int n0 = blockIdx.x * 128;
  const unsigned short* We = W + (size_t)e * wstride;

  if (tid < 128) {
    const int tk = rowtok[mt * 128 + tid];
    toks[tid] = tk;
    gns[tid] = (tk >= 0) ? gn[(size_t)tk * NEXP + e] : 0.f;
    b1s[tid] = b1[(size_t)e * FDIM + n0 + tid];
  }

  const int r0l = tid >> 2;
  const int cb = (tid & 3) * 8;
  int tka = rowtok[mt * 128 + r0l];      if (tka < 0) tka = 0;
  int tkb = rowtok[mt * 128 + 64 + r0l]; if (tkb < 0) tkb = 0;
  const unsigned short* ag0 = xb + (size_t)tka * DDIM + cb;
  const unsigned short* ag1 = xb + (size_t)tkb * DDIM + cb;
  const unsigned short* bg0 = We + (size_t)(n0 + r0l) * DDIM + cb;
  const unsigned short* bg1 = We + (size_t)(n0 + 64 + r0l) * DDIM + cb;
  const int w512 = (tid >> 6) * 512;
  unsigned short* la0 = As + w512;
  unsigned short* la1 = As + 2048 + w512;
  unsigned short* lb0 = Bs + w512;
  unsigned short* lb1 = Bs + 2048 + w512;

  const int lane = tid & 63;
  const int wm = ((tid >> 6) >> 1) * 64, wn = ((tid >> 6) & 1) * 64;
  const int fr = lane & 15, fk = (lane >> 4) * 8;

  f32x4 acc[4][4];
#pragma unroll
  for (int i = 0; i < 4; ++i)
#pragma unroll
    for (int j = 0; j < 4; ++j) acc[i][j] = (f32x4){0.f, 0.f, 0.f, 0.f};

  for (int k0 = 0; k0 < DDIM; k0 += 32) {
    __syncthreads();
    gl_lds16(ag0 + k0, la0);
    gl_lds16(ag1 + k0, la1);
    gl_lds16(bg0 + k0, lb0);
    gl_lds16(bg1 + k0, lb1);
    __syncthreads();
    bf16x8 af[4], bfv[4];
#pragma unroll
    for (int i = 0; i < 4; ++i) af[i] = *(const bf16x8*)&As[(wm + i * 16 + fr) * 32 + fk];
#pragma unroll
    for (int j = 0; j < 4; ++j) bfv[j] = *(const bf16x8*)&Bs[(wn + j * 16 + fr) * 32 + fk];
#pragma unroll
    for (int i = 0; i < 4; ++i)
#pragma unroll
      for (int j = 0; j < 4; ++j)
        acc[i][j] = __builtin_amdgcn_mfma_f32_16x16x32_bf16(af[i], bfv[j], acc[i][j], 0, 0, 0);
  }
#pragma unroll
  for (int i = 0; i < 4; ++i)
#pragma unroll
    for (int j = 0; j < 4; ++j) {
      const int col = wn + j * 16 + fr;
#pragma unroll
      for (int r = 0; r < 4; ++r) {
        const int row = wm + i * 16 + (lane >> 4) * 4 + r;
        if (toks[row] >= 0) {
          float v = acc[i][j][r] + b1s[col];
          v = 0.5f * v * (1.f + erff(v * 0.70710678118654752f));
          v *= gns[row];
          hb[(size_t)(mt * 128 + row - hbase) * FDIM + n0 + col] = f2bf(v);
        }
      }
    }
}

// ---------------- GEMM2: out = hb @ W2^T  (mode0: scatter += y, mode1: store partial) ----------------
__global__ __launch_bounds__(256) void gemm_o(
    const unsigned short* __restrict__ hb,   // compact [rows][FDIM] bf16
    const unsigned short* __restrict__ W,    // [DDIM][FDIM] bf16 (transposed), per-expert stride
    size_t wstride,
    const int* __restrict__ rowtok,
    const int* __restrict__ offs,
    int efix,
    float* __restrict__ yout,
    int mode)
{
  __shared__ unsigned short As[128 * 32];
  __shared__ unsigned short Bs[128 * 32];
  __shared__ int toks[128];
  const int tid = threadIdx.x;

  int mt, e, hbase;
  if (efix >= 0) {
    e = efix;
    hbase = offs[e];
    mt = (hbase >> 7) + blockIdx.y;
    if (mt * 128 >= offs[e + 1]) return;
  } else {
    mt = blockIdx.y;
    const int r0 = mt * 128;
    if (r0 >= offs[8]) return;
    e = 0;
#pragma unroll
    for (int q = 1; q < 8; ++q) if (r0 >= offs[q]) e = q;
    hbase = 0;
  }
  const int n0 = blockIdx.x * 128;
  const unsigned short* We = W + (size_t)e * wstride;

  if (tid < 128) toks[tid] = rowtok[mt * 128 + tid];

  const int r0l = tid >> 2;
  const int cb = (tid & 3) * 8;
  const unsigned short* ag0 = hb + (size_t)(mt * 128 + r0l - hbase) * FDIM + cb;
  const unsigned short* ag1 = hb + (size_t)(mt * 128 + 64 + r0l - hbase) * FDIM + cb;
  const unsigned short* bg0 = We + (size_t)(n0 + r0l) * FDIM + cb;
  const unsigned short* bg1 = We + (size_t)(n0 + 64 + r0l) * FDIM + cb;
  const int w512 = (tid >> 6) * 512;
  unsigned short* la0 = As + w512;
  unsigned short* la1 = As + 2048 + w512;
  unsigned short* lb0 = Bs + w512;
  unsigned short* lb1 = Bs + 2048 + w512;

  const int lane = tid & 63;
  const int wm = ((tid >> 6) >> 1) * 64, wn = ((tid >> 6) & 1) * 64;
  const int fr = lane & 15, fk = (lane >> 4) * 8;

  f32x4 acc[4][4];
#pragma unroll
  for (int i = 0; i < 4; ++i)
#pragma unroll
    for (int j = 0; j < 4; ++j) acc[i][j] = (f32x4){0.f, 0.f, 0.f, 0.f};

  for (int k0 = 0; k0 < FDIM; k0 += 32) {
    __syncthreads();
    gl_lds16(ag0 + k0, la0);
    gl_lds16(ag1 + k0, la1);
    gl_lds16(bg0 + k0, lb0);
    gl_lds16(bg1 + k0, lb1);
    __syncthreads();
    bf16x8 af[4], bfv[4];
#pragma unroll
    for (int i = 0; i < 4; ++i) af[i] = *(const bf16x8*)&As[(wm + i * 16 + fr) * 32 + fk];
#pragma unroll
    for (int j = 0; j < 4; ++j) bfv[j] = *(const bf16x8*)&Bs[(wn + j * 16 + fr) * 32 + fk];
#pragma unroll
    for (int i = 0; i < 4; ++i)
#pragma unroll
      for (int j = 0; j < 4; ++j)
        acc[i][j] = __builtin_amdgcn_mfma_f32_16x16x32_bf16(af[i], bfv[j], acc[i][j], 0, 0, 0);
  }
#pragma unroll
  for (int i = 0; i < 4; ++i)
#pragma unroll
    for (int j = 0; j < 4; ++j) {
      const int col = wn + j * 16 + fr;
#pragma unroll
      for (int r = 0; r < 4; ++r) {
        const int row = wm + i * 16 + (lane >> 4) * 4 + r;
        if (mode == 0) {
          const int tk = toks[row];
          if (tk >= 0) yout[(size_t)tk * DDIM + n0 + col] += acc[i][j][r];
        } else {
          yout[(size_t)(mt * 128 + row) * DDIM + n0 + col] = acc[i][j][r];
        }
      }
    }
}

// ---------------- combine (grouped path): y = sum over active rows + gn*b2 ----------------
__global__ __launch_bounds__(256) void combine_kernel(
    const float* __restrict__ hb2, const int* __restrict__ rowof,
    const float* __restrict__ gn, const float* __restrict__ b2,
    float* __restrict__ y)
{
  const int t = blockIdx.y;
  const int d = blockIdx.x * 256 + threadIdx.x;
  float s = 0.f;
#pragma unroll
  for (int e = 0; e < NEXP; ++e) {
    s += gn[(size_t)t * NEXP + e] * b2[(size_t)e * DDIM + d];
    const int r = rowof[(size_t)t * NEXP + e];
    if (r >= 0) s += hb2[(size_t)r * DDIM + d];
  }
  y[(size_t)t * DDIM + d] = s;
}

extern "C" void kernel_launch(void* const* d_in, const int* in_sizes, int n_in,
                              void* d_out, int out_size, void* d_ws, size_t ws_size,
                              hipStream_t stream) {
  (void)in_sizes; (void)n_in; (void)out_size;
  const float* x    = (const float*)d_in[0];
  const float* prev = (const float*)d_in[1];
  const float* Wt   = (const float*)d_in[2];
  const float* Wgt  = (const float*)d_in[3];
  const float* Wel  = (const float*)d_in[4];
  const float* W1   = (const float*)d_in[5];
  const float* b1   = (const float*)d_in[6];
  const float* W2   = (const float*)d_in[7];
  const float* b2   = (const float*)d_in[8];

  float* y      = (float*)d_out;
  float* logits = y + (size_t)NTOK * DDIM;

  char* ws = (char*)d_ws;
  size_t pos = 0;
  auto take = [&](size_t bytes) -> char* {
    char* r = ws + pos; pos += (bytes + 255) & ~(size_t)255; return r;
  };
  float* gn            = (float*)take((size_t)NTOK * NEXP * 4);
  int* cnt             = (int*)take(64);
  int* offs            = (int*)take(64);
  int* rowtok          = (int*)take((size_t)MAXROWS * 4);
  int* rowof           = (int*)take((size_t)NTOK * NEXP * 4);
  unsigned short* xb   = (unsigned short*)take((size_t)NTOK * DDIM * 2);
  const size_t fixed = pos;

  const size_t wexp = (size_t)FDIM * DDIM;  // elements per expert weight
  const size_t needA = fixed + 2 * NEXP * wexp * 2 + (size_t)MAXROWS * FDIM * 2
                       + (size_t)MAXROWS * DDIM * 4 + 4096;
  const bool tierA = ws_size >= needA;

  router_kernel<<<dim3(NTOK / 4), dim3(256), 0, stream>>>(x, prev, Wt, Wgt, Wel, gn, logits);
  cast_kernel<<<dim3((NTOK * DDIM) / (8 * 256)), dim3(256), 0, stream>>>(x, xb);
  count_kernel<<<dim3(NEXP), dim3(256), 0, stream>>>(gn, cnt);
  compact_kernel<<<dim3(NEXP), dim3(256), 0, stream>>>(gn, cnt, offs, rowtok, rowof);

  if (tierA) {
    unsigned short* W1b = (unsigned short*)take(NEXP * wexp * 2);
    unsigned short* W2b = (unsigned short*)take(NEXP * wexp * 2);
    unsigned short* hb  = (unsigned short*)take((size_t)MAXROWS * FDIM * 2);
    float* hb2          = (float*)take((size_t)MAXROWS * DDIM * 4);

    transcvt<<<dim3(FDIM / 64, DDIM / 64, NEXP), dim3(256), 0, stream>>>(W1, W1b, DDIM, FDIM);
    transcvt<<<dim3(DDIM / 64, FDIM / 64, NEXP), dim3(256), 0, stream>>>(W2, W2b, FDIM, DDIM);
    gemm_h<<<dim3(FDIM / 128, MAXROWS / 128), dim3(256), 0, stream>>>(
        xb, W1b, wexp, b1, gn, rowtok, offs, -1, hb);
    gemm_o<<<dim3(DDIM / 128, MAXROWS / 128), dim3(256), 0, stream>>>(
        hb, W2b, wexp, rowtok, offs, -1, hb2, 1);
    combine_kernel<<<dim3(DDIM / 256, NTOK), dim3(256), 0, stream>>>(hb2, rowof, gn, b2, y);
  } else {
    unsigned short* Wb = (unsigned short*)take(wexp * 2);
    unsigned short* hb = (unsigned short*)take((size_t)NTOK * FDIM * 2);

    y_init_kernel<<<dim3(DDIM / 256, NTOK), dim3(256), 0, stream>>>(gn, b2, y);
    for (int e = 0; e < NEXP; ++e) {
      transcvt<<<dim3(FDIM / 64, DDIM / 64, 1), dim3(256), 0, stream>>>(
          W1 + (size_t)e * wexp, Wb, DDIM, FDIM);
      gemm_h<<<dim3(FDIM / 128, 64), dim3(256), 0, stream>>>(
          xb, Wb, 0, b1, gn, rowtok, offs, e, hb);
      transcvt<<<dim3(DDIM / 64, FDIM / 64, 1), dim3(256), 0, stream>>>(
          W2 + (size_t)e * wexp, Wb, FDIM, DDIM);
      gemm_o<<<dim3(DDIM / 128, 64), dim3(256), 0, stream>>>(
          hb, Wb, 0, rowtok, offs, e, y, 0);
    }
  }
}

// Round 3
// 524.499 us; speedup vs baseline: 5.8698x; 1.0966x over previous
//
#include <hip/hip_runtime.h>
#include <math.h>

#define NTOK 8192   // B*S
#define DDIM 1024
#define NEXP 8
#define FDIM 4096
#define MAXROWS 25600   // <=3 active experts/token (softmax sum bound) + per-expert pad

typedef short bf16x8 __attribute__((ext_vector_type(8)));
typedef float f32x4 __attribute__((ext_vector_type(4)));

static __device__ __forceinline__ unsigned short f2bf(float f) {
  unsigned int u = __float_as_uint(f);
  u += 0x7fffu + ((u >> 16) & 1u);
  return (unsigned short)(u >> 16);
}

static __device__ __forceinline__ void gl_lds16(const void* g, void* l) {
  __builtin_amdgcn_global_load_lds(
      (const __attribute__((address_space(1))) unsigned int*)g,
      (__attribute__((address_space(3))) unsigned int*)l, 16, 0, 0);
}

// ---------------- router (fp32, mask-exact) ----------------
__global__ __launch_bounds__(256) void router_kernel(
    const float* __restrict__ x, const float* __restrict__ prev,
    const float* __restrict__ Wt, const float* __restrict__ Wgt,
    const float* __restrict__ Wel,
    float* __restrict__ gn, float* __restrict__ logits_out)
{
  __shared__ float wt_s[NEXP * DDIM];
  const int tid = threadIdx.x;
  for (int i = tid; i < NEXP * DDIM; i += 256) wt_s[i] = Wt[i];
  __syncthreads();
  const int lane = tid & 63;
  const int t = blockIdx.x * 4 + (tid >> 6);

  const float* xr = x + (size_t)t * DDIM;
  float acc[NEXP];
#pragma unroll
  for (int e = 0; e < NEXP; ++e) acc[e] = 0.f;
  for (int k = lane; k < DDIM; k += 64) {
    float xv = xr[k];
#pragma unroll
    for (int e = 0; e < NEXP; ++e) acc[e] += xv * wt_s[e * DDIM + k];
  }
#pragma unroll
  for (int e = 0; e < NEXP; ++e) {
    float v = acc[e];
#pragma unroll
    for (int off = 32; off >= 1; off >>= 1) v += __shfl_xor(v, off);
    acc[e] = v;
  }
  float pl[NEXP];
#pragma unroll
  for (int e = 0; e < NEXP; ++e) pl[e] = prev[(size_t)t * NEXP + e];
#pragma unroll
  for (int e = 0; e < NEXP; ++e) {
    float s = acc[e];
#pragma unroll
    for (int e2 = 0; e2 < NEXP; ++e2) s += pl[e2] * Wgt[e * NEXP + e2];
    acc[e] = s;
  }
  float mx = acc[0];
#pragma unroll
  for (int e = 1; e < NEXP; ++e) mx = fmaxf(mx, acc[e]);
  float st[NEXP]; float se = 0.f;
#pragma unroll
  for (int e = 0; e < NEXP; ++e) { st[e] = expf(acc[e] - mx); se += st[e]; }
  float inv = 1.f / se;
  float g[NEXP]; float gs = 0.f;
#pragma unroll
  for (int e = 0; e < NEXP; ++e) {
    float s = st[e] * inv;
    float we = 1.f / (1.f + expf(-Wel[e]));
    float gg = (s > 0.5f * we) ? s : 0.f;
    g[e] = gg; gs += gg;
  }
  float r = 1.f / (gs + 1e-6f);
  if (lane < NEXP) {
    gn[(size_t)t * NEXP + lane] = g[lane] * r;
    logits_out[(size_t)t * NEXP + lane] = acc[lane];
  }
}

// ---------------- x f32 -> bf16 ----------------
__global__ __launch_bounds__(256) void cast_kernel(
    const float* __restrict__ in, unsigned short* __restrict__ out)
{
  size_t i = ((size_t)blockIdx.x * 256 + threadIdx.x) * 8;
  float4 a = *(const float4*)(in + i);
  float4 b = *(const float4*)(in + i + 4);
  unsigned short tb[8];
  tb[0]=f2bf(a.x); tb[1]=f2bf(a.y); tb[2]=f2bf(a.z); tb[3]=f2bf(a.w);
  tb[4]=f2bf(b.x); tb[5]=f2bf(b.y); tb[6]=f2bf(b.z); tb[7]=f2bf(b.w);
  *(uint4*)(out + i) = *(const uint4*)tb;
}

// ---------------- count active tokens per expert ----------------
__global__ __launch_bounds__(256) void count_kernel(
    const float* __restrict__ gn, int* __restrict__ cnt)
{
  const int e = blockIdx.x, tid = threadIdx.x;
  int c = 0;
  for (int t = tid; t < NTOK; t += 256) c += (gn[(size_t)t * NEXP + e] > 0.f) ? 1 : 0;
#pragma unroll
  for (int o = 32; o >= 1; o >>= 1) c += __shfl_xor(c, o);
  __shared__ int sm[4];
  if ((tid & 63) == 0) sm[tid >> 6] = c;
  __syncthreads();
  if (tid == 0) cnt[e] = sm[0] + sm[1] + sm[2] + sm[3];
}

// ---------------- compact token lists (deterministic, token order) ----------------
__global__ __launch_bounds__(256) void compact_kernel(
    const float* __restrict__ gn, const int* __restrict__ cnt,
    int* __restrict__ offs, int* __restrict__ rowtok, int* __restrict__ rowof)
{
  const int e = blockIdx.x, tid = threadIdx.x;
  int base = 0;
#pragma unroll
  for (int q = 0; q < 8; ++q) if (q < e) base += (cnt[q] + 127) & ~127;
  const int padcnt = (cnt[e] + 127) & ~127;
  if (e == 0 && tid == 0) {
    int a = 0; offs[0] = 0;
#pragma unroll
    for (int q = 0; q < 8; ++q) { a += (cnt[q] + 127) & ~127; offs[q + 1] = a; }
  }
  __shared__ int wsm[4];
  __shared__ int running;
  if (tid == 0) running = 0;
  __syncthreads();
  const int lane = tid & 63, wv = tid >> 6;
  for (int c0 = 0; c0 < NTOK; c0 += 256) {
    const int t = c0 + tid;
    const bool pr = gn[(size_t)t * NEXP + e] > 0.f;
    unsigned long long bal = __ballot(pr);
    int pre = __popcll(bal & ((1ull << lane) - 1ull));
    if (lane == 0) wsm[wv] = __popcll(bal);
    __syncthreads();
    int wbase = 0;
#pragma unroll
    for (int q = 0; q < 4; ++q) if (q < wv) wbase += wsm[q];
    const int tot = wsm[0] + wsm[1] + wsm[2] + wsm[3];
    const int idx = base + running + wbase + pre;
    if (pr) rowtok[idx] = t;
    rowof[(size_t)t * NEXP + e] = pr ? idx : -1;
    __syncthreads();
    if (tid == 0) running += tot;
  }
  __syncthreads();
  for (int i = cnt[e] + tid; i < padcnt; i += 256) rowtok[base + i] = -1;
}

// ---------------- y := sum_e gn*b2 (per-expert path) ----------------
__global__ __launch_bounds__(256) void y_init_kernel(
    const float* __restrict__ gn, const float* __restrict__ b2,
    float* __restrict__ y)
{
  const int t = blockIdx.y;
  const int d = blockIdx.x * 256 + threadIdx.x;
  float s = 0.f;
#pragma unroll
  for (int e = 0; e < NEXP; ++e) s += gn[(size_t)t * NEXP + e] * b2[(size_t)e * DDIM + d];
  y[(size_t)t * DDIM + d] = s;
}

// ---------------- transpose+convert: in f32 [Kin][Nin] -> out bf16 [Nin][Kin] ----------------
__global__ __launch_bounds__(256) void transcvt(
    const float* __restrict__ in, unsigned short* __restrict__ out,
    int Kin, int Nin)
{
  __shared__ float tile[64][65];
  const size_t zo = (size_t)blockIdx.z * Kin * Nin;
  const float* inp = in + zo;
  unsigned short* outp = out + zo;
  const int k0 = blockIdx.y * 64, n0 = blockIdx.x * 64;
  const int tid = threadIdx.x;
  const int r = tid >> 4, c4 = (tid & 15) * 4;
#pragma unroll
  for (int rr = 0; rr < 64; rr += 16) {
    float4 v = *(const float4*)(inp + (size_t)(k0 + r + rr) * Nin + n0 + c4);
    tile[r + rr][c4] = v.x; tile[r + rr][c4 + 1] = v.y;
    tile[r + rr][c4 + 2] = v.z; tile[r + rr][c4 + 3] = v.w;
  }
  __syncthreads();
#pragma unroll
  for (int it = 0; it < 2; ++it) {
    const int o = it * 256 + tid;
    const int n = o >> 3, ks = (o & 7) * 8;
    unsigned short tb[8];
#pragma unroll
    for (int j = 0; j < 8; ++j) tb[j] = f2bf(tile[ks + j][n]);
    *(uint4*)(outp + (size_t)(n0 + n) * Kin + k0 + ks) = *(const uint4*)tb;
  }
}

// ---------------- GEMM1: h' = gn * gelu(gather(xb) @ W1^T) ----------------
__global__ __launch_bounds__(256) void gemm_h(
    const unsigned short* __restrict__ xb,   // [NTOK][DDIM] bf16
    const unsigned short* __restrict__ W,    // [FDIM][DDIM] bf16 (transposed), per-expert stride
    size_t wstride,
    const float* __restrict__ b1,            // [E][FDIM]
    const float* __restrict__ gn,            // [NTOK][E]
    const int* __restrict__ rowtok,
    const int* __restrict__ offs,            // [9], multiples of 128
    int efix,
    unsigned short* __restrict__ hb)         // compact [rows][FDIM] bf16
{
  __shared__ unsigned short As[2][128 * 32];
  __shared__ unsigned short Bs[2][128 * 32];
  __shared__ float gns[128];
  __shared__ float b1s[128];
  __shared__ int toks[128];
  const int tid = threadIdx.x;

  int mt, e, hbase;
  if (efix >= 0) {
    e = efix;
    hbase = offs[e];
    mt = (hbase >> 7) + blockIdx.y;
    if (mt * 128 >= offs[e + 1]) return;
  } else {
    mt = blockIdx.y;
    const int r0 = mt * 128;
    if (r0 >= offs[8]) return;
    e = 0;
#pragma unroll
    for (int q = 1; q < 8; ++q) if (r0 >= offs[q]) e = q;
    hbase = 0;
  }
  const int n0 = blockIdx.x * 128;
  const unsigned short* We = W + (size_t)e * wstride;

  if (tid < 128) {
    const int tk = rowtok[mt * 128 + tid];
    toks[tid] = tk;
    gns[tid] = (tk >= 0) ? gn[(size_t)tk * NEXP + e] : 0.f;
    b1s[tid] = b1[(size_t)e * FDIM + n0 + tid];
  }

  const int r0l = tid >> 2;
  const int cb = (tid & 3) * 8;
  int tka = rowtok[mt * 128 + r0l];      if (tka < 0) tka = 0;
  int tkb = rowtok[mt * 128 + 64 + r0l]; if (tkb < 0) tkb = 0;
  const unsigned short* ag0 = xb + (size_t)tka * DDIM + cb;
  const unsigned short* ag1 = xb + (size_t)tkb * DDIM + cb;
  const unsigned short* bg0 = We + (size_t)(n0 + r0l) * DDIM + cb;
  const unsigned short* bg1 = We + (size_t)(n0 + 64 + r0l) * DDIM + cb;
  const int w512 = (tid >> 6) * 512;
  unsigned short* laA0 = &As[0][w512];
  unsigned short* laA1 = &As[0][2048 + w512];
  unsigned short* laB0 = &Bs[0][w512];
  unsigned short* laB1 = &Bs[0][2048 + w512];

  const int lane = tid & 63;
  const int wm = ((tid >> 6) >> 1) * 64, wn = ((tid >> 6) & 1) * 64;
  const int fr = lane & 15, fk = (lane >> 4) * 8;

  f32x4 acc[4][4];
#pragma unroll
  for (int i = 0; i < 4; ++i)
#pragma unroll
    for (int j = 0; j < 4; ++j) acc[i][j] = (f32x4){0.f, 0.f, 0.f, 0.f};

  // prologue: stage tile 0 into buffer 0
  gl_lds16(ag0, laA0); gl_lds16(ag1, laA1);
  gl_lds16(bg0, laB0); gl_lds16(bg1, laB1);
  __syncthreads();   // drains vmcnt(0) then barrier

  int buf = 0;
  for (int k0 = 0; k0 < DDIM; k0 += 32) {
    // issue next tile's loads while computing this one (T3 minimal 2-phase)
    if (k0 + 32 < DDIM) {
      const int o = (buf ^ 1) * 4096;
      gl_lds16(ag0 + k0 + 32, laA0 + o);
      gl_lds16(ag1 + k0 + 32, laA1 + o);
      gl_lds16(bg0 + k0 + 32, laB0 + o);
      gl_lds16(bg1 + k0 + 32, laB1 + o);
    }
    const unsigned short* Ab = &As[buf][0];
    const unsigned short* Bb = &Bs[buf][0];
    bf16x8 af[4], bfv[4];
#pragma unroll
    for (int i = 0; i < 4; ++i) af[i] = *(const bf16x8*)&Ab[(wm + i * 16 + fr) * 32 + fk];
#pragma unroll
    for (int j = 0; j < 4; ++j) bfv[j] = *(const bf16x8*)&Bb[(wn + j * 16 + fr) * 32 + fk];
#pragma unroll
    for (int i = 0; i < 4; ++i)
#pragma unroll
      for (int j = 0; j < 4; ++j)
        acc[i][j] = __builtin_amdgcn_mfma_f32_16x16x32_bf16(af[i], bfv[j], acc[i][j], 0, 0, 0);
    __syncthreads();   // vmcnt(0)+lgkmcnt(0) drain + barrier: next buffer ready
    buf ^= 1;
  }
#pragma unroll
  for (int i = 0; i < 4; ++i)
#pragma unroll
    for (int j = 0; j < 4; ++j) {
      const int col = wn + j * 16 + fr;
#pragma unroll
      for (int r = 0; r < 4; ++r) {
        const int row = wm + i * 16 + (lane >> 4) * 4 + r;
        if (toks[row] >= 0) {
          float v = acc[i][j][r] + b1s[col];
          v = 0.5f * v * (1.f + erff(v * 0.70710678118654752f));
          v *= gns[row];
          hb[(size_t)(mt * 128 + row - hbase) * FDIM + n0 + col] = f2bf(v);
        }
      }
    }
}

// ---------------- GEMM2: out = hb @ W2^T  (mode0: scatter += y, mode1: store partial) ----------------
__global__ __launch_bounds__(256) void gemm_o(
    const unsigned short* __restrict__ hb,   // compact [rows][FDIM] bf16
    const unsigned short* __restrict__ W,    // [DDIM][FDIM] bf16 (transposed), per-expert stride
    size_t wstride,
    const int* __restrict__ rowtok,
    const int* __restrict__ offs,
    int efix,
    float* __restrict__ yout,
    int mode)
{
  __shared__ unsigned short As[2][128 * 32];
  __shared__ unsigned short Bs[2][128 * 32];
  __shared__ int toks[128];
  const int tid = threadIdx.x;

  int mt, e, hbase;
  if (efix >= 0) {
    e = efix;
    hbase = offs[e];
    mt = (hbase >> 7) + blockIdx.y;
    if (mt * 128 >= offs[e + 1]) return;
  } else {
    mt = blockIdx.y;
    const int r0 = mt * 128;
    if (r0 >= offs[8]) return;
    e = 0;
#pragma unroll
    for (int q = 1; q < 8; ++q) if (r0 >= offs[q]) e = q;
    hbase = 0;
  }
  const int n0 = blockIdx.x * 128;
  const unsigned short* We = W + (size_t)e * wstride;

  if (tid < 128) toks[tid] = rowtok[mt * 128 + tid];

  const int r0l = tid >> 2;
  const int cb = (tid & 3) * 8;
  const unsigned short* ag0 = hb + (size_t)(mt * 128 + r0l - hbase) * FDIM + cb;
  const unsigned short* ag1 = hb + (size_t)(mt * 128 + 64 + r0l - hbase) * FDIM + cb;
  const unsigned short* bg0 = We + (size_t)(n0 + r0l) * FDIM + cb;
  const unsigned short* bg1 = We + (size_t)(n0 + 64 + r0l) * FDIM + cb;
  const int w512 = (tid >> 6) * 512;
  unsigned short* laA0 = &As[0][w512];
  unsigned short* laA1 = &As[0][2048 + w512];
  unsigned short* laB0 = &Bs[0][w512];
  unsigned short* laB1 = &Bs[0][2048 + w512];

  const int lane = tid & 63;
  const int wm = ((tid >> 6) >> 1) * 64, wn = ((tid >> 6) & 1) * 64;
  const int fr = lane & 15, fk = (lane >> 4) * 8;

  f32x4 acc[4][4];
#pragma unroll
  for (int i = 0; i < 4; ++i)
#pragma unroll
    for (int j = 0; j < 4; ++j) acc[i][j] = (f32x4){0.f, 0.f, 0.f, 0.f};

  gl_lds16(ag0, laA0); gl_lds16(ag1, laA1);
  gl_lds16(bg0, laB0); gl_lds16(bg1, laB1);
  __syncthreads();

  int buf = 0;
  for (int k0 = 0; k0 < FDIM; k0 += 32) {
    if (k0 + 32 < FDIM) {
      const int o = (buf ^ 1) * 4096;
      gl_lds16(ag0 + k0 + 32, laA0 + o);
      gl_lds16(ag1 + k0 + 32, laA1 + o);
      gl_lds16(bg0 + k0 + 32, laB0 + o);
      gl_lds16(bg1 + k0 + 32, laB1 + o);
    }
    const unsigned short* Ab = &As[buf][0];
    const unsigned short* Bb = &Bs[buf][0];
    bf16x8 af[4], bfv[4];
#pragma unroll
    for (int i = 0; i < 4; ++i) af[i] = *(const bf16x8*)&Ab[(wm + i * 16 + fr) * 32 + fk];
#pragma unroll
    for (int j = 0; j < 4; ++j) bfv[j] = *(const bf16x8*)&Bb[(wn + j * 16 + fr) * 32 + fk];
#pragma unroll
    for (int i = 0; i < 4; ++i)
#pragma unroll
      for (int j = 0; j < 4; ++j)
        acc[i][j] = __builtin_amdgcn_mfma_f32_16x16x32_bf16(af[i], bfv[j], acc[i][j], 0, 0, 0);
    __syncthreads();
    buf ^= 1;
  }
#pragma unroll
  for (int i = 0; i < 4; ++i)
#pragma unroll
    for (int j = 0; j < 4; ++j) {
      const int col = wn + j * 16 + fr;
#pragma unroll
      for (int r = 0; r < 4; ++r) {
        const int row = wm + i * 16 + (lane >> 4) * 4 + r;
        if (mode == 0) {
          const int tk = toks[row];
          if (tk >= 0) yout[(size_t)tk * DDIM + n0 + col] += acc[i][j][r];
        } else {
          yout[(size_t)(mt * 128 + row) * DDIM + n0 + col] = acc[i][j][r];
        }
      }
    }
}

// ---------------- combine (grouped path): y = sum over active rows + gn*b2 ----------------
__global__ __launch_bounds__(256) void combine_kernel(
    const float* __restrict__ hb2, const int* __restrict__ rowof,
    const float* __restrict__ gn, const float* __restrict__ b2,
    float* __restrict__ y)
{
  const int t = blockIdx.y;
  const int d = blockIdx.x * 256 + threadIdx.x;
  float s = 0.f;
#pragma unroll
  for (int e = 0; e < NEXP; ++e) {
    s += gn[(size_t)t * NEXP + e] * b2[(size_t)e * DDIM + d];
    const int r = rowof[(size_t)t * NEXP + e];
    if (r >= 0) s += hb2[(size_t)r * DDIM + d];
  }
  y[(size_t)t * DDIM + d] = s;
}

extern "C" void kernel_launch(void* const* d_in, const int* in_sizes, int n_in,
                              void* d_out, int out_size, void* d_ws, size_t ws_size,
                              hipStream_t stream) {
  (void)in_sizes; (void)n_in; (void)out_size;
  const float* x    = (const float*)d_in[0];
  const float* prev = (const float*)d_in[1];
  const float* Wt   = (const float*)d_in[2];
  const float* Wgt  = (const float*)d_in[3];
  const float* Wel  = (const float*)d_in[4];
  const float* W1   = (const float*)d_in[5];
  const float* b1   = (const float*)d_in[6];
  const float* W2   = (const float*)d_in[7];
  const float* b2   = (const float*)d_in[8];

  float* y      = (float*)d_out;
  float* logits = y + (size_t)NTOK * DDIM;

  char* ws = (char*)d_ws;
  size_t pos = 0;
  auto take = [&](size_t bytes) -> char* {
    char* r = ws + pos; pos += (bytes + 255) & ~(size_t)255; return r;
  };
  float* gn            = (float*)take((size_t)NTOK * NEXP * 4);
  int* cnt             = (int*)take(64);
  int* offs            = (int*)take(64);
  int* rowtok          = (int*)take((size_t)MAXROWS * 4);
  int* rowof           = (int*)take((size_t)NTOK * NEXP * 4);
  unsigned short* xb   = (unsigned short*)take((size_t)NTOK * DDIM * 2);
  const size_t fixed = pos;

  const size_t wexp = (size_t)FDIM * DDIM;  // elements per expert weight
  const size_t needA = fixed + 2 * NEXP * wexp * 2 + (size_t)MAXROWS * FDIM * 2
                       + (size_t)MAXROWS * DDIM * 4 + 4096;
  const bool tierA = ws_size >= needA;

  router_kernel<<<dim3(NTOK / 4), dim3(256), 0, stream>>>(x, prev, Wt, Wgt, Wel, gn, logits);
  cast_kernel<<<dim3((NTOK * DDIM) / (8 * 256)), dim3(256), 0, stream>>>(x, xb);
  count_kernel<<<dim3(NEXP), dim3(256), 0, stream>>>(gn, cnt);
  compact_kernel<<<dim3(NEXP), dim3(256), 0, stream>>>(gn, cnt, offs, rowtok, rowof);

  if (tierA) {
    unsigned short* W1b = (unsigned short*)take(NEXP * wexp * 2);
    unsigned short* W2b = (unsigned short*)take(NEXP * wexp * 2);
    unsigned short* hb  = (unsigned short*)take((size_t)MAXROWS * FDIM * 2);
    float* hb2          = (float*)take((size_t)MAXROWS * DDIM * 4);

    transcvt<<<dim3(FDIM / 64, DDIM / 64, NEXP), dim3(256), 0, stream>>>(W1, W1b, DDIM, FDIM);
    transcvt<<<dim3(DDIM / 64, FDIM / 64, NEXP), dim3(256), 0, stream>>>(W2, W2b, FDIM, DDIM);
    gemm_h<<<dim3(FDIM / 128, MAXROWS / 128), dim3(256), 0, stream>>>(
        xb, W1b, wexp, b1, gn, rowtok, offs, -1, hb);
    gemm_o<<<dim3(DDIM / 128, MAXROWS / 128), dim3(256), 0, stream>>>(
        hb, W2b, wexp, rowtok, offs, -1, hb2, 1);
    combine_kernel<<<dim3(DDIM / 256, NTOK), dim3(256), 0, stream>>>(hb2, rowof, gn, b2, y);
  } else {
    unsigned short* Wb = (unsigned short*)take(wexp * 2);
    unsigned short* hb = (unsigned short*)take((size_t)NTOK * FDIM * 2);

    y_init_kernel<<<dim3(DDIM / 256, NTOK), dim3(256), 0, stream>>>(gn, b2, y);
    for (int e = 0; e < NEXP; ++e) {
      transcvt<<<dim3(FDIM / 64, DDIM / 64, 1), dim3(256), 0, stream>>>(
          W1 + (size_t)e * wexp, Wb, DDIM, FDIM);
      gemm_h<<<dim3(FDIM / 128, 64), dim3(256), 0, stream>>>(
          xb, Wb, 0, b1, gn, rowtok, offs, e, hb);
      transcvt<<<dim3(DDIM / 64, FDIM / 64, 1), dim3(256), 0, stream>>>(
          W2 + (size_t)e * wexp, Wb, FDIM, DDIM);
      gemm_o<<<dim3(DDIM / 128, 64), dim3(256), 0, stream>>>(
          hb, Wb, 0, rowtok, offs, e, y, 0);
    }
  }
}